// Round 6
// baseline (175.858 us; speedup 1.0000x reference)
//
#include <hip/hip_runtime.h>

// SNN forward — R10: ONE kernel (prep folded in) + grid-stride pipelined tiles.
//
// Key finding (R7/R8/R9 vs R0/R5): a second (prep) dispatch costs ~27us of
// harness-measured time (gap 91-97us two-kernel vs 63-67us single-kernel).
// R10 returns to a single dispatch:
//   - per-wave smx/mxmax: 32 coalesced W2 column loads + width-32 shuffle
//     reduce (identical math to the verified prep kernel), L1/L2-hot.
//   - layer 1 uses W1 directly via uniform scalar loads with the R4-verified
//     expression chain (absmax 0.0 at R0 bench).
// Plus software pipelining: 4 tiles of 512 rows per block; wave-private
// double-buffered LDS x-stage; tile t+1 global loads issued before tile t
// compute so HBM latency hides under compute+stores. Zero barriers.
// Dense waves (~9%) store their whole 1280-dword out region per-lane
// (every byte exactly once, full line coverage) -> no out-LDS, no hazards.
//
// Exactness (absmax 0.0 across R0-R9):
//  - layer-1 chain: h = x0*w0; h+=x1*w1; ... (R4 form, verbatim).
//  - gates: popc(m)*mxmax < 1.998 and S=sum smx[i] < 1.998 imply reference
//    h2[j] < 2.0 (fp sum err <= 31*2^-24*Sum|terms| ~ 4e-5 << margin).
//  - dense fallback: verbatim ascending set-bit order (R4-R9 verified).

typedef float v4f __attribute__((ext_vector_type(4)));
typedef float v2f __attribute__((ext_vector_type(2)));

#define TPB 256
#define RPL 2                    // rows per lane per tile
#define TROWS (64 * RPL)         // 128 rows per wave per tile
#define TILE (TPB * RPL)         // 512 rows per block per tile
#define NTILES 4
#define BROWS (TILE * NTILES)    // 2048 rows per block

__global__ __launch_bounds__(TPB) void snn_all(
    const float* __restrict__ x,
    const float* __restrict__ W1,   // [32,5]
    const float* __restrict__ W2,   // [32,32]
    const float* __restrict__ W3,   // [16,32]
    const float* __restrict__ W4,   // [10,16]
    float* __restrict__ out,        // [B,10]
    int B)
{
    __shared__ __align__(16) float xs[4][2][TROWS * 5];  // 20KB: 4 waves x dbuf
    __shared__ float smxl[4][32];                        // per-wave smx copy

    const int t = threadIdx.x;
    const int wv = t >> 6, lane = t & 63;
    const long blk0 = (long)blockIdx.x * BROWS;
    if (blk0 >= B) return;

    const bool fullblk = (blk0 + BROWS <= B);

    // ---- issue tile-0 x loads FIRST (critical path) ----
    v4f g[3];
    if (fullblk) {
        const v4f* xg = (const v4f*)(x + (blk0 + (long)wv * TROWS) * 5);
#pragma unroll
        for (int e = 0; e < 3; ++e) {
            int idx = e * 64 + lane;
            if (idx < (TROWS * 5) / 4) g[e] = xg[idx];
        }
    }

    // ---- per-wave smx/mxmax (math identical to verified prep kernel) ----
    const int col = lane & 31;
    float cm = W2[col];
#pragma unroll
    for (int j = 1; j < 32; ++j) cm = fmaxf(cm, W2[j * 32 + col]);
    smxl[wv][col] = cm;              // both half-waves write same value
    float mxmax = cm;
#pragma unroll
    for (int off = 16; off; off >>= 1)
        mxmax = fmaxf(mxmax, __shfl_xor(mxmax, off, 32));
    const float* __restrict__ smx = smxl[wv];

    if (fullblk) {
        for (int tt = 0; tt < NTILES; ++tt) {
            const long wt0 = blk0 + (long)tt * TILE + (long)wv * TROWS;
            float* sb = xs[wv][tt & 1];
            v4f* s4 = (v4f*)sb;

            // stage current tile's x regs -> LDS (vmcnt wait auto)
#pragma unroll
            for (int e = 0; e < 3; ++e) {
                int idx = e * 64 + lane;
                if (idx < (TROWS * 5) / 4) s4[idx] = g[e];
            }

            // prefetch next tile's x (latency hides under compute below)
            if (tt + 1 < NTILES) {
                const v4f* xg =
                    (const v4f*)(x + (blk0 + (long)(tt + 1) * TILE +
                                      (long)wv * TROWS) * 5);
#pragma unroll
                for (int e = 0; e < 3; ++e) {
                    int idx = e * 64 + lane;
                    if (idx < (TROWS * 5) / 4) g[e] = xg[idx];
                }
            }

            // own 10 x floats back (in-order DS per wave; lgkmcnt auto)
            v2f xp[5];
            {
                const v2f* sx = (const v2f*)(sb + lane * 10);
#pragma unroll
                for (int e = 0; e < 5; ++e) xp[e] = sx[e];
            }
            const float* xf = (const float*)xp;

            // ---- layer 1: R4-verified scalar chain, j-outer (uniform W1
            //      -> scalar loads), 2 rows amortize each weight row ----
            unsigned m[RPL] = {0u, 0u};
#pragma unroll
            for (int j = 0; j < 32; ++j) {
                const float* w = W1 + j * 5;
#pragma unroll
                for (int c = 0; c < RPL; ++c) {
                    float h = xf[c * 5 + 0] * w[0];
                    h += xf[c * 5 + 1] * w[1];
                    h += xf[c * 5 + 2] * w[2];
                    h += xf[c * 5 + 3] * w[3];
                    h += xf[c * 5 + 4] * w[4];
                    if (h >= 2.0f) m[c] |= (1u << j);
                }
            }

            // ---- gates; find dense rows ----
            bool dense[RPL];
            unsigned m2s[RPL];
            bool any_dense = false;
#pragma unroll
            for (int c = 0; c < RPL; ++c) {
                dense[c] = false;
                m2s[c] = 0u;
                const unsigned mc = m[c];
                if (mc && ((float)__popc(mc) * mxmax >= 1.998f)) {
                    float S = 0.0f;
                    unsigned mm = mc;
                    while (mm) { int i = __ffs(mm) - 1; mm &= mm - 1; S += smx[i]; }
                    if (S >= 1.998f) {
                        // dense layer 2: VERBATIM verified ascending-bit order
                        float h2[32];
#pragma unroll
                        for (int j = 0; j < 32; ++j) h2[j] = 0.0f;
                        mm = mc;
                        while (mm) {
                            const int i = __ffs(mm) - 1;
                            mm &= mm - 1;
                            const float* colp = W2 + i;  // W2^T[i][j]==W2[j*32+i]
#pragma unroll
                            for (int j = 0; j < 32; ++j) h2[j] += colp[j * 32];
                        }
                        unsigned m2 = 0u;
#pragma unroll
                        for (int j = 0; j < 32; ++j)
                            if (h2[j] >= 2.0f) m2 |= (1u << j);
                        m2s[c] = m2;
                        if (m2) { dense[c] = true; any_dense = true; }
                    }
                }
            }

            if (!__any(any_dense)) {
                // ---- common (~91% of waves): coalesced zero-burst ----
                v4f z = {0.0f, 0.0f, 0.0f, 0.0f};
                v4f* og = (v4f*)(out + wt0 * 10);
#pragma unroll
                for (int e = 0; e < 5; ++e) og[e * 64 + lane] = z;
            } else {
                // ---- rare wave: each lane stores its own 2 rows fully
                //      (1280 dwords/wave, every byte exactly once) ----
                float oo[RPL][10];
#pragma unroll
                for (int c = 0; c < RPL; ++c)
#pragma unroll
                    for (int j = 0; j < 10; ++j) oo[c][j] = 0.0f;
#pragma unroll
                for (int c = 0; c < RPL; ++c) {
                    if (!dense[c]) continue;
                    const unsigned m2 = m2s[c];
                    unsigned m3 = 0u;
#pragma unroll
                    for (int j = 0; j < 16; ++j) {
                        float gg = 0.0f;
#pragma unroll
                        for (int i = 0; i < 32; ++i)
                            if ((m2 >> i) & 1u) gg += W3[j * 32 + i];
                        if (gg >= 2.0f) m3 |= (1u << j);
                    }
#pragma unroll
                    for (int j = 0; j < 10; ++j) {
                        float gg = 0.0f;
#pragma unroll
                        for (int i = 0; i < 16; ++i)
                            if ((m3 >> i) & 1u) gg += W4[j * 16 + i];
                        oo[c][j] = (gg >= 2.0f) ? 1.0f : 0.0f;
                    }
                }
#pragma unroll
                for (int c = 0; c < RPL; ++c) {
                    float* orow = out + (wt0 + (long)lane * RPL + c) * 10;
#pragma unroll
                    for (int j = 0; j < 10; ++j) orow[j] = oo[c][j];
                }
            }
        }
    } else {
        // ---- tail block (not hit at B=2^21; correctness-general) ----
        const long rend = (blk0 + BROWS < (long)B) ? blk0 + BROWS : (long)B;
        for (long r = blk0 + t; r < rend; r += TPB) {
            float xr[5];
#pragma unroll
            for (int k = 0; k < 5; ++k) xr[k] = x[r * 5 + k];
            unsigned mc = 0u;
#pragma unroll
            for (int j = 0; j < 32; ++j) {
                const float* w = W1 + j * 5;
                float h = xr[0] * w[0];
                h += xr[1] * w[1];
                h += xr[2] * w[2];
                h += xr[3] * w[3];
                h += xr[4] * w[4];
                if (h >= 2.0f) mc |= (1u << j);
            }
            float o[10];
#pragma unroll
            for (int j = 0; j < 10; ++j) o[j] = 0.0f;
            if (mc && ((float)__popc(mc) * mxmax >= 1.998f)) {
                float S = 0.0f;
                unsigned mm = mc;
                while (mm) { int i = __ffs(mm) - 1; mm &= mm - 1; S += smx[i]; }
                if (S >= 1.998f) {
                    float h2[32];
#pragma unroll
                    for (int j = 0; j < 32; ++j) h2[j] = 0.0f;
                    mm = mc;
                    while (mm) {
                        const int i = __ffs(mm) - 1;
                        mm &= mm - 1;
                        const float* colp = W2 + i;
#pragma unroll
                        for (int j = 0; j < 32; ++j) h2[j] += colp[j * 32];
                    }
                    unsigned m2 = 0u;
#pragma unroll
                    for (int j = 0; j < 32; ++j)
                        if (h2[j] >= 2.0f) m2 |= (1u << j);
                    if (m2) {
                        unsigned m3 = 0u;
#pragma unroll
                        for (int j = 0; j < 16; ++j) {
                            float gg = 0.0f;
#pragma unroll
                            for (int i = 0; i < 32; ++i)
                                if ((m2 >> i) & 1u) gg += W3[j * 32 + i];
                            if (gg >= 2.0f) m3 |= (1u << j);
                        }
#pragma unroll
                        for (int j = 0; j < 10; ++j) {
                            float gg = 0.0f;
#pragma unroll
                            for (int i = 0; i < 16; ++i)
                                if ((m3 >> i) & 1u) gg += W4[j * 16 + i];
                            o[j] = (gg >= 2.0f) ? 1.0f : 0.0f;
                        }
                    }
                }
            }
#pragma unroll
            for (int j = 0; j < 10; ++j) out[r * 10 + j] = o[j];
        }
    }
}

extern "C" void kernel_launch(void* const* d_in, const int* in_sizes, int n_in,
                              void* d_out, int out_size, void* d_ws, size_t ws_size,
                              hipStream_t stream) {
    const float* x  = (const float*)d_in[0];
    const float* W1 = (const float*)d_in[1];
    const float* W2 = (const float*)d_in[2];
    const float* W3 = (const float*)d_in[3];
    const float* W4 = (const float*)d_in[4];
    float* out = (float*)d_out;

    int B = in_sizes[0] / 5;
    int grid = (B + BROWS - 1) / BROWS;
    snn_all<<<grid, TPB, 0, stream>>>(x, W1, W2, W3, W4, out, B);
}

// Round 7
// 136.666 us; speedup vs baseline: 1.2868x; 1.2868x over previous
//
#include <hip/hip_runtime.h>

// SNN forward — R11: single kernel, R8 skeleton, WAVE-COOPERATIVE dense path.
//
// Six-round record: dispatch pinned 67-90us with VALU-issue ~20us and
// mandatory HBM ~17us, across occupancy 19-61%, barriers/none, NT/cached.
// Last unablated structure: the divergent dense path (serial per-lane
// h2[32] + ~160 scattered stride-128B W2 loads per event, under divergent
// exec; fires in ~9% of waves, unhidable at 2-3 resident waves/SIMD).
//
// R11 changes:
//  - gates only FLAG dense rows; layer-2+ moved to a wave-cooperative
//    section: per dense row, broadcast mask; lane j<32 computes h2[j] from
//    a register-preloaded W2 row via 32 predicated adds (compile-time
//    indices); ballot -> m2; lanes <16 / <10 handle W3/W4 rows the same.
//  - unconditional coalesced zero-burst for every wave (no out-LDS);
//    dense rows overwrite their 40B after s_waitcnt(0) (rare path).
//
// Exactness (absmax 0.0 across R0-R10):
//  - layer-1: R4/R10-verified scalar chain (h=x0*w0; h+=x1*w1; ...).
//  - gates: popc(m)*mxmax < 1.998 and S=sum smx[i] < 1.998 imply reference
//    h2[j] < 2.0 (fp sum err <= 31*2^-24*Sum|terms| ~ 4e-5 << margin).
//  - predicated add of literal +0.0f is an IEEE identity (x + (+0) = x for
//    all finite x except x=-0 -> +0, and h2/g3/g4 feed ONLY >= compares;
//    outputs are 0.0f/1.0f literals) => trajectory == the verified
//    ascending-set-bit skip form, per output neuron, ascending i.
//  - per-wave smx/mxmax scan: verbatim R10 (verified).

typedef float v4f __attribute__((ext_vector_type(4)));
typedef float v2f __attribute__((ext_vector_type(2)));

#define TPB 256
#define RPL 2                  // rows per lane
#define TROWS (64 * RPL)       // 128 rows per wave
#define RPB (TPB * RPL)        // 512 rows per block

__global__ __launch_bounds__(TPB) void snn_one(
    const float* __restrict__ x,
    const float* __restrict__ W1,   // [32,5]
    const float* __restrict__ W2,   // [32,32]
    const float* __restrict__ W3,   // [16,32]
    const float* __restrict__ W4,   // [10,16]
    float* __restrict__ out,        // [B,10]
    int B)
{
    __shared__ __align__(16) float xsh[4][TROWS * 5];   // 10KB: wave-private x
    __shared__ float smxl[4][32];

    const int t = threadIdx.x;
    const int wv = t >> 6, lane = t & 63;
    float* sb = xsh[wv];
    const long wt0 = (long)blockIdx.x * RPB + (long)wv * TROWS;
    if (wt0 >= B) return;

    const bool full = (wt0 + TROWS <= B);

    // ---- issue this wave's x loads FIRST (hide under colmax scan) ----
    v4f g0, g1, g2;
    if (full) {
        const v4f* xg = (const v4f*)(x + wt0 * 5);
        g0 = xg[lane];
        g1 = xg[64 + lane];
        if (lane < 32) g2 = xg[128 + lane];   // 160 v4f total
    }

    // ---- per-wave smx/mxmax (verbatim R10, verified) ----
    const int col = lane & 31;
    float cm = W2[col];
#pragma unroll
    for (int j = 1; j < 32; ++j) cm = fmaxf(cm, W2[j * 32 + col]);
    smxl[wv][col] = cm;                 // duplicate same-value write is benign
    float mxmax = cm;
#pragma unroll
    for (int off = 16; off; off >>= 1)
        mxmax = fmaxf(mxmax, __shfl_xor(mxmax, off, 32));
    const float* __restrict__ smx = smxl[wv];

    if (full) {
        // ---- stage x -> wave-private LDS, read back own 2 rows ----
        v4f* s4 = (v4f*)sb;
        s4[lane] = g0;
        s4[64 + lane] = g1;
        if (lane < 32) s4[128 + lane] = g2;

        v2f xp[5];
        {
            const v2f* sx = (const v2f*)(sb + lane * 10);
#pragma unroll
            for (int e = 0; e < 5; ++e) xp[e] = sx[e];
        }
        const float* xf = (const float*)xp;

        // ---- layer 1: R4-verified scalar chain, j-outer ----
        unsigned m[RPL] = {0u, 0u};
#pragma unroll
        for (int j = 0; j < 32; ++j) {
            const float* w = W1 + j * 5;
#pragma unroll
            for (int c = 0; c < RPL; ++c) {
                float h = xf[c * 5 + 0] * w[0];
                h += xf[c * 5 + 1] * w[1];
                h += xf[c * 5 + 2] * w[2];
                h += xf[c * 5 + 3] * w[3];
                h += xf[c * 5 + 4] * w[4];
                if (h >= 2.0f) m[c] |= (1u << j);
            }
        }

        // ---- gates -> dense flags only (no compute here) ----
        bool dense[RPL];
#pragma unroll
        for (int c = 0; c < RPL; ++c) {
            dense[c] = false;
            const unsigned mc = m[c];
            if (mc && ((float)__popc(mc) * mxmax >= 1.998f)) {
                float S = 0.0f;
                unsigned mm = mc;
                while (mm) { int i = __ffs(mm) - 1; mm &= mm - 1; S += smx[i]; }
                dense[c] = (S >= 1.998f);
            }
        }

        // ---- unconditional coalesced zero-burst (every wave) ----
        {
            v4f z = {0.0f, 0.0f, 0.0f, 0.0f};
            v4f* og = (v4f*)(out + wt0 * 10);
#pragma unroll
            for (int e = 0; e < 5; ++e) og[e * 64 + lane] = z;
        }

        // ---- cooperative dense path (rare: ~9% of waves) ----
        if (__any(dense[0] || dense[1])) {
            // preload W2 row j=lane&31 into regs (4KB wave-coalesced, L2-hot)
            v4f w2r[8];
            {
                const v4f* wr = (const v4f*)(W2 + (lane & 31) * 32);
#pragma unroll
                for (int e = 0; e < 8; ++e) w2r[e] = wr[e];
            }
            const float* w2f = (const float*)w2r;

#pragma unroll
            for (int c = 0; c < RPL; ++c) {
                unsigned long long dmask = __ballot(dense[c]);
                while (dmask) {
                    const int L = (int)__ffsll(dmask) - 1;
                    dmask &= dmask - 1;
                    const unsigned mrow = __shfl(m[c], L);   // uniform bcast

                    // h2[j] for j=lane (lanes 0..31), ascending i,
                    // predicated +0.0 identity == verified skip form
                    float h2 = 0.0f;
#pragma unroll
                    for (int i = 0; i < 32; ++i)
                        h2 += ((mrow >> i) & 1u) ? w2f[i] : 0.0f;
                    const unsigned m2 =
                        (unsigned)__ballot(lane < 32 && h2 >= 2.0f);

                    if (m2) {   // ultra-rare
                        float g3 = 0.0f;
                        if (lane < 16) {
                            const float* w3r = W3 + lane * 32;
#pragma unroll
                            for (int i = 0; i < 32; ++i)
                                g3 += ((m2 >> i) & 1u) ? w3r[i] : 0.0f;
                        }
                        const unsigned m3 =
                            (unsigned)__ballot(lane < 16 && g3 >= 2.0f);
                        if (m3) {
                            float g4 = 0.0f;
                            if (lane < 10) {
                                const float* w4r = W4 + lane * 16;
#pragma unroll
                                for (int i = 0; i < 16; ++i)
                                    g4 += ((m3 >> i) & 1u) ? w4r[i] : 0.0f;
                            }
                            __builtin_amdgcn_s_waitcnt(0);  // order vs zero-burst
                            if (lane < 10)
                                out[(wt0 + (long)L * RPL + c) * 10 + lane] =
                                    (g4 >= 2.0f) ? 1.0f : 0.0f;
                        }
                    }
                }
            }
        }
    } else {
        // ---- tail wave (not hit at B=2^21; correctness-general, serial) ----
        for (int c = 0; c < RPL; ++c) {
            const long r = wt0 + (long)lane * RPL + c;
            if (r >= B) continue;
            float xr[5];
#pragma unroll
            for (int k = 0; k < 5; ++k) xr[k] = x[r * 5 + k];
            unsigned mc = 0u;
#pragma unroll
            for (int j = 0; j < 32; ++j) {
                const float* w = W1 + j * 5;
                float h = xr[0] * w[0];
                h += xr[1] * w[1];
                h += xr[2] * w[2];
                h += xr[3] * w[3];
                h += xr[4] * w[4];
                if (h >= 2.0f) mc |= (1u << j);
            }
            float o[10];
#pragma unroll
            for (int j = 0; j < 10; ++j) o[j] = 0.0f;
            if (mc && ((float)__popc(mc) * mxmax >= 1.998f)) {
                float S = 0.0f;
                unsigned mm = mc;
                while (mm) { int i = __ffs(mm) - 1; mm &= mm - 1; S += smx[i]; }
                if (S >= 1.998f) {
                    float h2[32];
#pragma unroll
                    for (int j = 0; j < 32; ++j) h2[j] = 0.0f;
                    mm = mc;
                    while (mm) {
                        const int i = __ffs(mm) - 1;
                        mm &= mm - 1;
                        const float* colp = W2 + i;
#pragma unroll
                        for (int j = 0; j < 32; ++j) h2[j] += colp[j * 32];
                    }
                    unsigned m2 = 0u;
#pragma unroll
                    for (int j = 0; j < 32; ++j)
                        if (h2[j] >= 2.0f) m2 |= (1u << j);
                    if (m2) {
                        unsigned m3 = 0u;
#pragma unroll
                        for (int j = 0; j < 16; ++j) {
                            float gg = 0.0f;
#pragma unroll
                            for (int i = 0; i < 32; ++i)
                                if ((m2 >> i) & 1u) gg += W3[j * 32 + i];
                            if (gg >= 2.0f) m3 |= (1u << j);
                        }
#pragma unroll
                        for (int j = 0; j < 10; ++j) {
                            float gg = 0.0f;
#pragma unroll
                            for (int i = 0; i < 16; ++i)
                                if ((m3 >> i) & 1u) gg += W4[j * 16 + i];
                            o[j] = (gg >= 2.0f) ? 1.0f : 0.0f;
                        }
                    }
                }
            }
#pragma unroll
            for (int j = 0; j < 10; ++j) out[r * 10 + j] = o[j];
        }
    }
}

extern "C" void kernel_launch(void* const* d_in, const int* in_sizes, int n_in,
                              void* d_out, int out_size, void* d_ws, size_t ws_size,
                              hipStream_t stream) {
    const float* x  = (const float*)d_in[0];
    const float* W1 = (const float*)d_in[1];
    const float* W2 = (const float*)d_in[2];
    const float* W3 = (const float*)d_in[3];
    const float* W4 = (const float*)d_in[4];
    float* out = (float*)d_out;

    int B = in_sizes[0] / 5;
    int grid = (B + RPB - 1) / RPB;
    snn_one<<<grid, TPB, 0, stream>>>(x, W1, W2, W3, W4, out, B);
}

// Round 8
// 135.101 us; speedup vs baseline: 1.3017x; 1.0116x over previous
//
#include <hip/hip_runtime.h>

// SNN forward — R12: R11 skeleton + packed-v2f layer-1 + early zero-burst.
//
// R11 result: cooperative dense path broke the 67us wall; kernel now <50us
// (hidden below the harness's 51us fill dispatches). Remaining consumers:
// layer-1 issue (~450 VALU instr/wave) and the x->LDS->readback/colmax
// latency chains, vs a ~12.5us pure-store floor (fill: 6.6 TB/s measured).
//
// R12 changes (both using forms already verified absmax=0.0):
//  1. layer-1 in packed v2f (R6/R7-verified bit-exact): 320 scalar FMA ->
//     160 packed ops/lane. W1 pair-vectors from uniform scalar loads
//     in-loop (SALU/K$ pipe, free alongside VALU).
//  2. zero-burst stores hoisted to the TOP of the wave (depend only on
//     wt0) -> write drain overlaps colmax scan + layer-1 compute.
//     Rare-path overwrite still ordered by s_waitcnt(0) (R11-verified).
//  3. gates / cooperative dense path / tail verbatim R11.
//
// Exactness:
//  - v2f chain h=x0*w; h+=x1*w; ... : each half is an independent scalar
//    chain in k-order == R4 scalar form; verified absmax 0.0 in R6 AND R7.
//  - gates: popc(m)*mxmax < 1.998 and S=sum smx[i] < 1.998 imply reference
//    h2[j] < 2.0 (fp sum err <= 31*2^-24*Sum|terms| ~ 4e-5 << margin).
//  - cooperative dense path: predicated +0.0 adds (IEEE identity; feeds
//    only >= compares), ascending i == verified skip form. R11-verified.

typedef float v4f __attribute__((ext_vector_type(4)));
typedef float v2f __attribute__((ext_vector_type(2)));

#define TPB 256
#define RPL 2                  // rows per lane
#define TROWS (64 * RPL)       // 128 rows per wave
#define RPB (TPB * RPL)        // 512 rows per block

__global__ __launch_bounds__(TPB) void snn_one(
    const float* __restrict__ x,
    const float* __restrict__ W1,   // [32,5]
    const float* __restrict__ W2,   // [32,32]
    const float* __restrict__ W3,   // [16,32]
    const float* __restrict__ W4,   // [10,16]
    float* __restrict__ out,        // [B,10]
    int B)
{
    __shared__ __align__(16) float xsh[4][TROWS * 5];   // 10KB: wave-private x
    __shared__ float smxl[4][32];

    const int t = threadIdx.x;
    const int wv = t >> 6, lane = t & 63;
    float* sb = xsh[wv];
    const long wt0 = (long)blockIdx.x * RPB + (long)wv * TROWS;
    if (wt0 >= B) return;

    const bool full = (wt0 + TROWS <= B);

    // ---- issue this wave's x loads FIRST ----
    v4f g0, g1, g2;
    if (full) {
        const v4f* xg = (const v4f*)(x + wt0 * 5);
        g0 = xg[lane];
        g1 = xg[64 + lane];
        if (lane < 32) g2 = xg[128 + lane];   // 160 v4f total
    }

    // ---- EARLY coalesced zero-burst: depends only on wt0; its drain
    //      overlaps the colmax scan + layer-1 below ----
    if (full) {
        v4f z = {0.0f, 0.0f, 0.0f, 0.0f};
        v4f* og = (v4f*)(out + wt0 * 10);
#pragma unroll
        for (int e = 0; e < 5; ++e) og[e * 64 + lane] = z;
    }

    // ---- per-wave smx/mxmax (verbatim R10/R11, verified) ----
    const int col = lane & 31;
    float cm = W2[col];
#pragma unroll
    for (int j = 1; j < 32; ++j) cm = fmaxf(cm, W2[j * 32 + col]);
    smxl[wv][col] = cm;                 // duplicate same-value write is benign
    float mxmax = cm;
#pragma unroll
    for (int off = 16; off; off >>= 1)
        mxmax = fmaxf(mxmax, __shfl_xor(mxmax, off, 32));
    const float* __restrict__ smx = smxl[wv];

    if (full) {
        // ---- stage x -> wave-private LDS, read back own 2 rows ----
        v4f* s4 = (v4f*)sb;
        s4[lane] = g0;
        s4[64 + lane] = g1;
        if (lane < 32) s4[128 + lane] = g2;

        v2f xp[5];
        {
            const v2f* sx = (const v2f*)(sb + lane * 10);
#pragma unroll
            for (int e = 0; e < 5; ++e) xp[e] = sx[e];
        }
        const float* xf = (const float*)xp;

        // ---- layer 1: packed v2f, j2-outer (R6/R7-verified math form);
        //      W1 pair-vectors from uniform scalar loads (SALU/K$) ----
        unsigned m[RPL] = {0u, 0u};
#pragma unroll
        for (int j2 = 0; j2 < 16; ++j2) {
            const float* wA = W1 + (2 * j2) * 5;
            const float* wB = W1 + (2 * j2 + 1) * 5;
            const v2f w0 = {wA[0], wB[0]};
            const v2f w1 = {wA[1], wB[1]};
            const v2f w2 = {wA[2], wB[2]};
            const v2f w3 = {wA[3], wB[3]};
            const v2f w4 = {wA[4], wB[4]};
#pragma unroll
            for (int c = 0; c < RPL; ++c) {
                v2f h = xf[c * 5 + 0] * w0;   // exact per-neuron chain order
                h += xf[c * 5 + 1] * w1;
                h += xf[c * 5 + 2] * w2;
                h += xf[c * 5 + 3] * w3;
                h += xf[c * 5 + 4] * w4;
                if (h.x >= 2.0f) m[c] |= (1u << (2 * j2));
                if (h.y >= 2.0f) m[c] |= (1u << (2 * j2 + 1));
            }
        }

        // ---- gates -> dense flags only (verbatim R11) ----
        bool dense[RPL];
#pragma unroll
        for (int c = 0; c < RPL; ++c) {
            dense[c] = false;
            const unsigned mc = m[c];
            if (mc && ((float)__popc(mc) * mxmax >= 1.998f)) {
                float S = 0.0f;
                unsigned mm = mc;
                while (mm) { int i = __ffs(mm) - 1; mm &= mm - 1; S += smx[i]; }
                dense[c] = (S >= 1.998f);
            }
        }

        // ---- cooperative dense path (verbatim R11, verified) ----
        if (__any(dense[0] || dense[1])) {
            // preload W2 row j=lane&31 into regs (4KB wave-coalesced, L2-hot)
            v4f w2r[8];
            {
                const v4f* wr = (const v4f*)(W2 + (lane & 31) * 32);
#pragma unroll
                for (int e = 0; e < 8; ++e) w2r[e] = wr[e];
            }
            const float* w2f = (const float*)w2r;

#pragma unroll
            for (int c = 0; c < RPL; ++c) {
                unsigned long long dmask = __ballot(dense[c]);
                while (dmask) {
                    const int L = (int)__ffsll(dmask) - 1;
                    dmask &= dmask - 1;
                    const unsigned mrow = __shfl(m[c], L);   // uniform bcast

                    // h2[j] for j=lane (lanes 0..31), ascending i,
                    // predicated +0.0 identity == verified skip form
                    float h2 = 0.0f;
#pragma unroll
                    for (int i = 0; i < 32; ++i)
                        h2 += ((mrow >> i) & 1u) ? w2f[i] : 0.0f;
                    const unsigned m2 =
                        (unsigned)__ballot(lane < 32 && h2 >= 2.0f);

                    if (m2) {   // ultra-rare
                        float g3 = 0.0f;
                        if (lane < 16) {
                            const float* w3r = W3 + lane * 32;
#pragma unroll
                            for (int i = 0; i < 32; ++i)
                                g3 += ((m2 >> i) & 1u) ? w3r[i] : 0.0f;
                        }
                        const unsigned m3 =
                            (unsigned)__ballot(lane < 16 && g3 >= 2.0f);
                        if (m3) {
                            float g4 = 0.0f;
                            if (lane < 10) {
                                const float* w4r = W4 + lane * 16;
#pragma unroll
                                for (int i = 0; i < 16; ++i)
                                    g4 += ((m3 >> i) & 1u) ? w4r[i] : 0.0f;
                            }
                            __builtin_amdgcn_s_waitcnt(0);  // order vs zero-burst
                            if (lane < 10)
                                out[(wt0 + (long)L * RPL + c) * 10 + lane] =
                                    (g4 >= 2.0f) ? 1.0f : 0.0f;
                        }
                    }
                }
            }
        }
    } else {
        // ---- tail wave (not hit at B=2^21; correctness-general, serial) ----
        for (int c = 0; c < RPL; ++c) {
            const long r = wt0 + (long)lane * RPL + c;
            if (r >= B) continue;
            float xr[5];
#pragma unroll
            for (int k = 0; k < 5; ++k) xr[k] = x[r * 5 + k];
            unsigned mc = 0u;
#pragma unroll
            for (int j = 0; j < 32; ++j) {
                const float* w = W1 + j * 5;
                float h = xr[0] * w[0];
                h += xr[1] * w[1];
                h += xr[2] * w[2];
                h += xr[3] * w[3];
                h += xr[4] * w[4];
                if (h >= 2.0f) mc |= (1u << j);
            }
            float o[10];
#pragma unroll
            for (int j = 0; j < 10; ++j) o[j] = 0.0f;
            if (mc && ((float)__popc(mc) * mxmax >= 1.998f)) {
                float S = 0.0f;
                unsigned mm = mc;
                while (mm) { int i = __ffs(mm) - 1; mm &= mm - 1; S += smx[i]; }
                if (S >= 1.998f) {
                    float h2[32];
#pragma unroll
                    for (int j = 0; j < 32; ++j) h2[j] = 0.0f;
                    mm = mc;
                    while (mm) {
                        const int i = __ffs(mm) - 1;
                        mm &= mm - 1;
                        const float* colp = W2 + i;
#pragma unroll
                        for (int j = 0; j < 32; ++j) h2[j] += colp[j * 32];
                    }
                    unsigned m2 = 0u;
#pragma unroll
                    for (int j = 0; j < 32; ++j)
                        if (h2[j] >= 2.0f) m2 |= (1u << j);
                    if (m2) {
                        unsigned m3 = 0u;
#pragma unroll
                        for (int j = 0; j < 16; ++j) {
                            float gg = 0.0f;
#pragma unroll
                            for (int i = 0; i < 32; ++i)
                                if ((m2 >> i) & 1u) gg += W3[j * 32 + i];
                            if (gg >= 2.0f) m3 |= (1u << j);
                        }
#pragma unroll
                        for (int j = 0; j < 10; ++j) {
                            float gg = 0.0f;
#pragma unroll
                            for (int i = 0; i < 16; ++i)
                                if ((m3 >> i) & 1u) gg += W4[j * 16 + i];
                            o[j] = (gg >= 2.0f) ? 1.0f : 0.0f;
                        }
                    }
                }
            }
#pragma unroll
            for (int j = 0; j < 10; ++j) out[r * 10 + j] = o[j];
        }
    }
}

extern "C" void kernel_launch(void* const* d_in, const int* in_sizes, int n_in,
                              void* d_out, int out_size, void* d_ws, size_t ws_size,
                              hipStream_t stream) {
    const float* x  = (const float*)d_in[0];
    const float* W1 = (const float*)d_in[1];
    const float* W2 = (const float*)d_in[2];
    const float* W3 = (const float*)d_in[3];
    const float* W4 = (const float*)d_in[4];
    float* out = (float*)d_out;

    int B = in_sizes[0] / 5;
    int grid = (B + RPB - 1) / RPB;
    snn_one<<<grid, TPB, 0, stream>>>(x, W1, W2, W3, W4, out, B);
}